// Round 1
// baseline (564.369 us; speedup 1.0000x reference)
//
#include <hip/hip_runtime.h>

// SCC (DSXplore sliding-channel conv) on MI355X.
// out[b,o,p] = sum_{j<256} w[o,j] * x[b, (o*128+j)%1024, p],  p in [0,3136)
//
// Key identity: o*128 mod 1024 has period 8 in o, so outputs with o%8==g all
// read the contiguous channel band [128g, 128g+256) mod 1024. The op is 8
// dense GEMMs: M=128 (outputs of group g), K=256 (band channels), N=b*3136.
//
// Round 1: fp32 VALU version (no fp32 MFMA on CDNA4). Block computes one
// (g, b, 64-wide spatial tile): 128x64 outputs, K chunked by 32 through LDS.
// W tile is stored transposed [k][m] (padded ld=132) so the inner loop is
// pure ds_read_b128 + v_fmac_f32.

#define B_      16
#define C_IN    1024
#define C_OUT   1024
#define UNIT    256
#define STRIDE_ 128     // unit - overlap (overlap=128 from setup_inputs)
#define HW      3136    // 56*56
#define GROUPS  8       // C_IN / gcd(STRIDE_, C_IN) ... period of o*128 mod 1024
#define MPG     128     // outputs per group = C_OUT / GROUPS
#define NT      64      // spatial tile (3136 = 49*64, exact)
#define KC      32      // K chunk
#define WLD     132     // padded leading dim of transposed W tile (132*4B % 16B == 0)

__global__ __launch_bounds__(256) void scc_fp32_kernel(
    const float* __restrict__ x, const float* __restrict__ w,
    float* __restrict__ out)
{
    __shared__ float Xs[KC][NT];    // [k][p]   8 KB
    __shared__ float Ws[KC][WLD];   // [k][m]  16.9 KB (transposed, padded)

    const int tid = threadIdx.x;
    const int p0  = blockIdx.x * NT;
    const int g   = blockIdx.y;
    const int b   = blockIdx.z;

    const int nx = (tid & 15) * 4;   // this thread's 4 spatial cols
    const int m0 = (tid >> 4) * 8;   // this thread's 8 output rows (within group)

    float acc[8][4];
#pragma unroll
    for (int i = 0; i < 8; i++)
#pragma unroll
        for (int j = 0; j < 4; j++) acc[i][j] = 0.f;

    const float* xbase = x + (size_t)b * C_IN * HW + p0;

    for (int k0 = 0; k0 < UNIT; k0 += KC) {
        __syncthreads();
        // ---- stage X chunk: KC x NT floats (512 float4, 2 per thread), coalesced
#pragma unroll
        for (int r = 0; r < 2; r++) {
            int f   = tid + 256 * r;
            int row = f >> 4;              // [0,32)
            int c4  = (f & 15) * 4;        // [0,64) step 4
            int ch  = (g * STRIDE_ + k0 + row) & (C_IN - 1);
            float4 v = *(const float4*)(xbase + (size_t)ch * HW + c4);
            *(float4*)(&Xs[row][c4]) = v;
        }
        // ---- stage W chunk transposed: rows m in [0,128), cols j in [k0,k0+KC)
        // 1024 float4 loads (4/thread), scatter to Ws[j][m]
#pragma unroll
        for (int r = 0; r < 4; r++) {
            int f  = tid + 256 * r;
            int m  = f >> 3;               // [0,128)
            int jj = (f & 7) * 4;          // [0,32) step 4
            float4 v = *(const float4*)(w + (size_t)(g + 8 * m) * UNIT + k0 + jj);
            Ws[jj + 0][m] = v.x;
            Ws[jj + 1][m] = v.y;
            Ws[jj + 2][m] = v.z;
            Ws[jj + 3][m] = v.w;
        }
        __syncthreads();
        // ---- inner product: 32 k-steps, 32 FMA each (outer product 8x4)
#pragma unroll
        for (int kk = 0; kk < KC; kk++) {
            float4 xv = *(const float4*)(&Xs[kk][nx]);
            float4 wa = *(const float4*)(&Ws[kk][m0]);
            float4 wb = *(const float4*)(&Ws[kk][m0 + 4]);
            float xs[4] = {xv.x, xv.y, xv.z, xv.w};
            float ws[8] = {wa.x, wa.y, wa.z, wa.w, wb.x, wb.y, wb.z, wb.w};
#pragma unroll
            for (int i = 0; i < 8; i++)
#pragma unroll
                for (int j = 0; j < 4; j++)
                    acc[i][j] += ws[i] * xs[j];
        }
    }

    // ---- epilogue: o = g + 8*(m0+i); 64 contiguous p per o-row
    float* obase = out + (size_t)b * C_OUT * HW + p0 + nx;
#pragma unroll
    for (int i = 0; i < 8; i++) {
        int o = g + 8 * (m0 + i);
        float4 v = {acc[i][0], acc[i][1], acc[i][2], acc[i][3]};
        *(float4*)(obase + (size_t)o * HW) = v;
    }
}

extern "C" void kernel_launch(void* const* d_in, const int* in_sizes, int n_in,
                              void* d_out, int out_size, void* d_ws, size_t ws_size,
                              hipStream_t stream)
{
    const float* x = (const float*)d_in[0];
    const float* w = (const float*)d_in[1];
    // d_in[2] = overlap (scalar, =128) — folded into STRIDE_ at compile time.
    float* out = (float*)d_out;

    dim3 grid(HW / NT, GROUPS, B_);   // (49, 8, 16) = 6272 blocks
    scc_fp32_kernel<<<grid, 256, 0, stream>>>(x, w, out);
}

// Round 2
// 382.405 us; speedup vs baseline: 1.4758x; 1.4758x over previous
//
#include <hip/hip_runtime.h>
#include <stdint.h>

// SCC (sliding-channel conv) = 8 dense group-GEMMs (o%8==g reads channel band
// [128g,128g+256) mod 1024). R2: bf16 MFMA 16x16x32.
//   - X (B-operand) loaded DIRECTLY global->register: B[k=quad*8+j][n=lane&15]
//     needs 8 strided dwords/lane; per instr = 4 channel-rows x 16 consecutive
//     p = coalesced 64B segments. Each x element touched once per block.
//   - W (A-operand) staged fp32->bf16 in LDS, XOR-swizzled 16B segments so
//     ds_read_b128 frag reads hit all 32 banks uniformly (no pad needed).
//   - acc fp32 in MFMA; wave = M128 x N16 strip; block = 128x64 out tile.

#define B_      16
#define C_IN    1024
#define C_OUT   1024
#define UNIT    256
#define STRIDE_ 128
#define HW      3136
#define NT      64      // spatial tile: 3136 = 49*64 exact
#define KC      64      // K chunk staged per barrier pair

typedef __attribute__((ext_vector_type(8))) short bf16x8;
typedef __attribute__((ext_vector_type(4))) float floatx4;
typedef __attribute__((ext_vector_type(4))) short short4v;

__device__ __forceinline__ short f2bf(float f) {
    // fp32 -> bf16, round-to-nearest-even
    uint32_t u = __float_as_uint(f);
    u += 0x7FFFu + ((u >> 16) & 1u);
    return (short)(u >> 16);
}

__global__ __launch_bounds__(256) void scc_mfma_kernel(
    const float* __restrict__ x, const float* __restrict__ w,
    float* __restrict__ out)
{
    __shared__ short Ws[128 * KC];   // 16 KB bf16, XOR-swizzled segments

    const int tid  = threadIdx.x;
    const int lane = tid & 63;
    const int wn   = tid >> 6;       // wave = one 16-wide N strip
    const int nq   = lane & 15;      // MFMA n-col / A-row index
    const int quad = lane >> 4;      // MFMA k-group

    const int p0 = blockIdx.x * NT;
    const int g  = blockIdx.y;
    const int b  = blockIdx.z;

    const int    p  = p0 + wn * 16 + nq;
    const float* xb = x + (size_t)b * C_IN * HW + p;

    floatx4 acc[8];
#pragma unroll
    for (int i = 0; i < 8; ++i) acc[i] = (floatx4){0.f, 0.f, 0.f, 0.f};

    char* wsb = (char*)Ws;

    for (int kc = 0; kc < UNIT / KC; ++kc) {
        const int k0 = kc * KC;
        __syncthreads();
        // ---- stage W chunk: rows m=0..127 (o=g+8m), cols k0..k0+63, fp32->bf16
        // segment s (8 bf16 = 16B) of row m stored at position s ^ (m&7)
#pragma unroll
        for (int r = 0; r < 8; ++r) {
            int f   = tid + 256 * r;          // 0..2047
            int m   = f >> 4;                 // 0..127
            int kk4 = (f & 15) * 4;           // 0..60
            float4 v = *(const float4*)(w + (size_t)(g + 8 * m) * UNIT + k0 + kk4);
            short4v s4 = { f2bf(v.x), f2bf(v.y), f2bf(v.z), f2bf(v.w) };
            int seg = kk4 >> 3;
            int off = m * 128 + (((seg ^ (m & 7)) * 16)) + ((kk4 & 4) * 2);
            *(short4v*)(wsb + off) = s4;
        }
        __syncthreads();

        // ---- 2 k-steps of 32; B-frags for both steps loaded up front (16
        // outstanding HBM dwords), then 16 MFMA + 16 ds_read_b128
        float bv[2][8];
#pragma unroll
        for (int kb2 = 0; kb2 < 2; ++kb2) {
            int kb = kc * 2 + kb2;
            // channel run g*128 + kb*32 + quad*8 + j never straddles the mod-1024
            // wrap (base is a multiple of 8, run length 8)
            int cb = (g * STRIDE_ + kb * 32 + quad * 8) & (C_IN - 1);
            const float* xp = xb + (size_t)cb * HW;
#pragma unroll
            for (int j = 0; j < 8; ++j) bv[kb2][j] = xp[(size_t)j * HW];
        }
#pragma unroll
        for (int kb2 = 0; kb2 < 2; ++kb2) {
            bf16x8 bfrag;
#pragma unroll
            for (int j = 0; j < 8; ++j) bfrag[j] = f2bf(bv[kb2][j]);
            const int aoff = nq * 128 + (((kb2 * 4 + quad) ^ (nq & 7)) * 16);
#pragma unroll
            for (int mf = 0; mf < 8; ++mf) {
                bf16x8 afrag = *(const bf16x8*)(wsb + mf * 2048 + aoff);
                acc[mf] = __builtin_amdgcn_mfma_f32_16x16x32_bf16(afrag, bfrag, acc[mf], 0, 0, 0);
            }
        }
    }

    // ---- epilogue: D col = nq (=p), row = quad*4 + reg within each 16-block;
    // o = g + 8*(mf*16 + quad*4 + reg) = g + 128*mf + 32*quad + 8*reg
    float* ob = out + ((size_t)b * C_OUT + g + 32 * quad) * HW + p;
#pragma unroll
    for (int mf = 0; mf < 8; ++mf) {
        float* o2 = ob + (size_t)(128 * mf) * HW;
#pragma unroll
        for (int reg = 0; reg < 4; ++reg)
            o2[(size_t)(8 * reg) * HW] = acc[mf][reg];
    }
}

extern "C" void kernel_launch(void* const* d_in, const int* in_sizes, int n_in,
                              void* d_out, int out_size, void* d_ws, size_t ws_size,
                              hipStream_t stream)
{
    const float* x = (const float*)d_in[0];
    const float* w = (const float*)d_in[1];
    float* out = (float*)d_out;

    dim3 grid(HW / NT, 8, B_);   // (49, 8, 16)
    scc_mfma_kernel<<<grid, 256, 0, stream>>>(x, w, out);
}